// Round 3
// baseline (1945.736 us; speedup 1.0000x reference)
//
#include <hip/hip_runtime.h>
#include <math.h>

// ---------------- constants ----------------
#define NTOK   1568
#define BATCH  2
#define HID    1024
#define MLPD   4096
#define NLAYER 4
#define ROWS   (BATCH*NTOK)   // 3136
#define CONVK  1536

typedef __bf16 bf16x8 __attribute__((ext_vector_type(8)));
typedef float  f32x4  __attribute__((ext_vector_type(4)));

__device__ __forceinline__ unsigned short f2b(float f) {
  unsigned int u = __float_as_uint(f);
  unsigned int r = u + 0x7FFFu + ((u >> 16) & 1u);   // RNE
  return (unsigned short)(r >> 16);
}
__device__ __forceinline__ float b2f(unsigned short s) {
  return __uint_as_float((unsigned int)s << 16);
}

// async global->LDS 16B; lds ptr must be wave-uniform base (HW adds lane*16)
__device__ __forceinline__ void async16(const unsigned short* g, unsigned short* l) {
  __builtin_amdgcn_global_load_lds(
      (__attribute__((address_space(1))) void*)(void*)g,
      (__attribute__((address_space(3))) void*)(void*)l, 16, 0, 0);
}

// ---------------- fp32 -> bf16 cast (x4 vectorized, grid-stride) ----------------
__global__ __launch_bounds__(256) void cast4_k(const float* __restrict__ s,
                                               unsigned short* __restrict__ d,
                                               long long n4) {
  long long i = (long long)blockIdx.x * 256 + threadIdx.x;
  long long stride = (long long)gridDim.x * 256;
  for (; i < n4; i += stride) {
    float4 v = ((const float4*)s)[i];
    *(ushort4*)(d + i * 4) = make_ushort4(f2b(v.x), f2b(v.y), f2b(v.z), f2b(v.w));
  }
}

// cast q/k/v weights into one concatenated per-layer buffer wQKV[L][3072][1024]
__global__ __launch_bounds__(256) void castqkv_k(const float* __restrict__ q,
                                                 const float* __restrict__ k,
                                                 const float* __restrict__ v,
                                                 unsigned short* __restrict__ dst) {
  const float* src = blockIdx.y == 0 ? q : (blockIdx.y == 1 ? k : v);
  long long i4 = (long long)blockIdx.x * 256 + threadIdx.x;   // exactly L*HH/4
  long long e = i4 * 4;
  int layer = (int)(e >> 20);                                  // HH = 1<<20
  long long de = e + ((long long)(2 * layer + blockIdx.y) << 20);
  float4 val = ((const float4*)src)[i4];
  *(ushort4*)(dst + de) = make_ushort4(f2b(val.x), f2b(val.y), f2b(val.z), f2b(val.w));
}

__global__ __launch_bounds__(256) void biascat_k(const float* __restrict__ qb,
                                                 const float* __restrict__ kb,
                                                 const float* __restrict__ vb,
                                                 float* __restrict__ dst) {
  int idx = blockIdx.x * 256 + threadIdx.x;   // L*3072
  int layer = idx / 3072, c = idx % 3072;
  float v = c < 1024 ? qb[layer * 1024 + c]
            : (c < 2048 ? kb[layer * 1024 + c - 1024] : vb[layer * 1024 + c - 2048]);
  dst[idx] = v;
}

// ---------------- im2col for the tubelet conv ----------------
__global__ __launch_bounds__(256) void im2col_k(const float* __restrict__ pv,
                                                unsigned short* __restrict__ A) {
  int idx = blockIdx.x * 256 + threadIdx.x;       // exactly ROWS*CONVK threads
  int row = idx / CONVK, col = idx % CONVK;
  int b = row / NTOK, t = row % NTOK;
  int d = t / 196, r = t % 196, hh = r / 14, ww = r % 14;
  int c = col >> 9, r2 = col & 511, td = r2 >> 8, ph = (r2 >> 4) & 15, pw = r2 & 15;
  int frame = 2 * d + td;
  const float* src = pv + ((((long long)b * 16 + frame) * 3 + c) * 224 + (hh * 16 + ph)) * 224
                        + (ww * 16 + pw);
  A[idx] = f2b(*src);
}

// ---------------- GEMM: C[M,N] = A[M,K](bf16) * B[N,K]^T(bf16) + bias ----------------
// EPI: 0 = fp32 out; 1 = fp32 out + resid; 2 = bf16 out; 3 = exact-GELU -> bf16 out
template <int EPI>
__global__ __launch_bounds__(256) void gemm_bt(const unsigned short* __restrict__ A,
                                               const unsigned short* __restrict__ B,
                                               const float* __restrict__ bias,
                                               const float* __restrict__ resid,
                                               float* __restrict__ outF,
                                               unsigned short* __restrict__ outB,
                                               int M, int N, int K) {
  __shared__ unsigned short As[128 * 32];
  __shared__ unsigned short Bs[128 * 32];
  const int tid = threadIdx.x;
  const int lane = tid & 63;
  const int w = tid >> 6;
  const int wm = (w >> 1) * 64, wn = (w & 1) * 64;
  const int l15 = lane & 15, l4 = lane >> 4;
  const int bm = blockIdx.y, bn = blockIdx.x;
  const int wbase = tid & ~63;   // wave-uniform

  f32x4 acc[4][4] = {};

  for (int k0 = 0; k0 < K; k0 += 32) {
    __syncthreads();
#pragma unroll
    for (int it = 0; it < 2; ++it) {
      int c = it * 256 + tid;
      int rowA = bm * 128 + (c >> 2);
      if (rowA >= M) rowA = M - 1;
      async16(A + (size_t)rowA * K + k0 + (c & 3) * 8, &As[(it * 256 + wbase) * 8]);
      int rowB = bn * 128 + (c >> 2);
      async16(B + (size_t)rowB * K + k0 + (c & 3) * 8, &Bs[(it * 256 + wbase) * 8]);
    }
    __syncthreads();

    bf16x8 af[4], bfr[4];
#pragma unroll
    for (int i = 0; i < 4; ++i) af[i]  = *(const bf16x8*)&As[(wm + i * 16 + l15) * 32 + l4 * 8];
#pragma unroll
    for (int j = 0; j < 4; ++j) bfr[j] = *(const bf16x8*)&Bs[(wn + j * 16 + l15) * 32 + l4 * 8];
#pragma unroll
    for (int i = 0; i < 4; ++i)
#pragma unroll
      for (int j = 0; j < 4; ++j)
        acc[i][j] = __builtin_amdgcn_mfma_f32_16x16x32_bf16(af[i], bfr[j], acc[i][j], 0, 0, 0);
  }

#pragma unroll
  for (int i = 0; i < 4; ++i) {
    int rowb = bm * 128 + wm + i * 16 + l4 * 4;
#pragma unroll
    for (int r = 0; r < 4; ++r) {
      int rr = rowb + r;
      if (rr >= M) continue;
#pragma unroll
      for (int j = 0; j < 4; ++j) {
        int col = bn * 128 + wn + j * 16 + l15;
        float v = acc[i][j][r] + bias[col];
        size_t o = (size_t)rr * N + col;
        if (EPI == 0) outF[o] = v;
        else if (EPI == 1) outF[o] = v + resid[o];
        else if (EPI == 2) outB[o] = f2b(v);
        else { float ge = 0.5f * v * (1.0f + erff(v * 0.70710678118654752f)); outB[o] = f2b(ge); }
      }
    }
  }
}

// ---------------- LayerNorm (row=1024) ----------------
template <int OUT_BF16>
__global__ __launch_bounds__(256) void ln_k(const float* __restrict__ x,
                                            const float* __restrict__ g,
                                            const float* __restrict__ b,
                                            unsigned short* __restrict__ oB,
                                            float* __restrict__ oF) {
  __shared__ float red[8];
  const int row = blockIdx.x, tid = threadIdx.x;
  const float4 v = ((const float4*)(x + (size_t)row * HID))[tid];
  float s = v.x + v.y + v.z + v.w;
  float q = v.x * v.x + v.y * v.y + v.z * v.z + v.w * v.w;
  for (int off = 32; off; off >>= 1) { s += __shfl_xor(s, off); q += __shfl_xor(q, off); }
  if ((tid & 63) == 0) { red[tid >> 6] = s; red[4 + (tid >> 6)] = q; }
  __syncthreads();
  float ts = red[0] + red[1] + red[2] + red[3];
  float tq = red[4] + red[5] + red[6] + red[7];
  float mu = ts * (1.0f / HID);
  float var = tq * (1.0f / HID) - mu * mu;
  float rs = rsqrtf(var + 1e-6f);
  int col = tid * 4;
  float o0 = (v.x - mu) * rs * g[col + 0] + b[col + 0];
  float o1 = (v.y - mu) * rs * g[col + 1] + b[col + 1];
  float o2 = (v.z - mu) * rs * g[col + 2] + b[col + 2];
  float o3 = (v.w - mu) * rs * g[col + 3] + b[col + 3];
  if (OUT_BF16) {
    *(ushort4*)(oB + (size_t)row * HID + col) = make_ushort4(f2b(o0), f2b(o1), f2b(o2), f2b(o3));
  } else {
    *(float4*)(oF + (size_t)row * HID + col) = make_float4(o0, o1, o2, o3);
  }
}

// ---------------- QKV prep: RoPE(q,k)+scale -> head-major; V -> per-head transposed ----
// grid (25 token-tiles, 32 bh); block 256
__global__ __launch_bounds__(256) void qkvprep_k(const unsigned short* __restrict__ qkvb,
                                                 unsigned short* __restrict__ Qh,
                                                 unsigned short* __restrict__ Kh,
                                                 unsigned short* __restrict__ VT) {
  __shared__ unsigned short Vs[64 * 72];
  const int tile = blockIdx.x, bh = blockIdx.y;
  const int b = bh >> 4, head = bh & 15;
  const int tid = threadIdx.x;
  const int tl = tid >> 2, dc = tid & 3;
  const int tg = tile * 64 + tl;
  const int trc = tg < NTOK ? tg : NTOK - 1;
  const bool valid = tg < NTOK;
  const size_t srow = ((size_t)(b * NTOK + trc)) * 3072 + head * 64 + dc * 16;

  // V chunk -> LDS
  {
    uint4 v0 = *(const uint4*)(qkvb + srow + 2048);
    uint4 v1 = *(const uint4*)(qkvb + srow + 2048 + 8);
    *(uint4*)&Vs[tl * 72 + dc * 16] = v0;
    *(uint4*)&Vs[tl * 72 + dc * 16 + 8] = v1;
  }

  // RoPE on q,k (8 pairs per thread)
  const int t = trc;
  const int dpos = t / 196, rem = t - dpos * 196, hpos = rem / 14, wpos = rem - hpos * 14;
  const float LG = 0.9210340371976184f;  // ln(10000)/10
  union V16 { uint4 u[2]; unsigned short s[16]; };
  V16 qin, kin, qout, kout;
  qin.u[0] = *(const uint4*)(qkvb + srow);
  qin.u[1] = *(const uint4*)(qkvb + srow + 8);
  kin.u[0] = *(const uint4*)(qkvb + srow + 1024);
  kin.u[1] = *(const uint4*)(qkvb + srow + 1024 + 8);
#pragma unroll
  for (int p = 0; p < 8; ++p) {
    int d0 = dc * 16 + 2 * p;
    float qx0 = b2f(qin.s[2 * p]), qx1 = b2f(qin.s[2 * p + 1]);
    float kx0 = b2f(kin.s[2 * p]), kx1 = b2f(kin.s[2 * p + 1]);
    float qo0, qo1, ko0, ko1;
    if (d0 >= 60) { qo0 = qx0; qo1 = qx1; ko0 = kx0; ko1 = kx1; }
    else {
      int region = d0 / 20;
      int j0 = d0 - region * 20;
      int pos = region == 0 ? dpos : (region == 1 ? hpos : wpos);
      float fp = (float)pos;
      int i0 = j0 % 10, i1 = (j0 + 1) % 10;
      float f0 = expf(-LG * (float)i0) * fp;
      float f1 = expf(-LG * (float)i1) * fp;
      float c0 = cosf(f0), s0 = sinf(f0), c1 = cosf(f1), s1 = sinf(f1);
      qo0 = qx0 * c0 - qx1 * s0; qo1 = qx1 * c1 + qx0 * s1;
      ko0 = kx0 * c0 - kx1 * s0; ko1 = kx1 * c1 + kx0 * s1;
    }
    qout.s[2 * p]     = f2b(qo0 * 0.125f);     // fold attention scale into Q
    qout.s[2 * p + 1] = f2b(qo1 * 0.125f);
    kout.s[2 * p]     = f2b(ko0);
    kout.s[2 * p + 1] = f2b(ko1);
  }
  if (valid) {
    size_t drow = ((size_t)bh * NTOK + tg) * 64 + dc * 16;
    *(uint4*)(Qh + drow)     = qout.u[0];
    *(uint4*)(Qh + drow + 8) = qout.u[1];
    *(uint4*)(Kh + drow)     = kout.u[0];
    *(uint4*)(Kh + drow + 8) = kout.u[1];
  }
  __syncthreads();
  // V transpose out: thread = (dim, token-chunk)
  {
    int d = tid >> 2, tc = tid & 3;
    if (tile * 64 + tc * 16 < NTOK) {
      V16 o;
#pragma unroll
      for (int jj = 0; jj < 16; ++jj) o.s[jj] = Vs[(tc * 16 + jj) * 72 + d];
      unsigned short* dst = VT + ((size_t)bh * 64 + d) * NTOK + tile * 64 + tc * 16;
      *(uint4*)dst = o.u[0];
      *(uint4*)(dst + 8) = o.u[1];
    }
  }
}

// ---------------- flash attention v3: register-double-buffered K, early V issue ------
// S^T = K·Q^T, O^T = V^T·P^T, no LDS/barriers in K-loop.
// grid (32 bh, 25 q-tiles), block 256 (4 waves); wave owns 16 q-rows, loops 25 key-tiles
__global__ __launch_bounds__(256, 2) void flash3_k(const unsigned short* __restrict__ Qh,
                                                   const unsigned short* __restrict__ Kh,
                                                   const unsigned short* __restrict__ VT,
                                                   unsigned short* __restrict__ O) {
  __shared__ unsigned short Os[4][16 * 72];
  const int bh = blockIdx.x, qt = blockIdx.y;
  const int b = bh >> 4, head = bh & 15;
  const int tid = threadIdx.x, lane = tid & 63, w = tid >> 6;
  const int l15 = lane & 15, l4 = lane >> 4;
  const size_t hb = (size_t)bh * NTOK * 64;

  const int qrow = qt * 64 + w * 16 + l15;
  const int qrc = qrow < NTOK ? qrow : NTOK - 1;
  // Q as B-operand: lane n=l15 (qrow), elements k=dim=l4*8+j  -> contiguous
  bf16x8 q0 = *(const bf16x8*)(Qh + hb + (size_t)qrc * 64 + l4 * 8);
  bf16x8 q1 = *(const bf16x8*)(Qh + hb + (size_t)qrc * 64 + 32 + l4 * 8);

  f32x4 oacc[4] = {};          // O^T tiles: row dim=dt*16+l4*4+r, col qrow=l15
  float m = -1e30f, l = 0.0f;  // per-qrow (lane-uniform across l4 group)
  const unsigned short* vbp = VT + (size_t)bh * 64 * NTOK;

  // K fragment double buffer (registers): preload tile 0
  bf16x8 kc0[4], kc1[4];
#pragma unroll
  for (int nt = 0; nt < 4; ++nt) {
    int kr = nt * 16 + l15;
    const unsigned short* kp = Kh + hb + (size_t)kr * 64 + l4 * 8;
    kc0[nt] = *(const bf16x8*)kp;
    kc1[nt] = *(const bf16x8*)(kp + 32);
  }

  for (int kt = 0; kt < 25; ++kt) {
    const int kb = kt * 64;

    // ---- issue V loads for THIS tile early (consumed only after softmax) ----
    bf16x8 vf0[4], vf1[4];
#pragma unroll
    for (int dt = 0; dt < 4; ++dt) {
      const unsigned short* vr = vbp + (size_t)(dt * 16 + l15) * NTOK + kb;
      vf0[dt] = *(const bf16x8*)(vr + l4 * 8);
      vf1[dt] = *(const bf16x8*)(vr + 32 + l4 * 8);
    }
    // ---- prefetch NEXT tile's K fragments ----
    bf16x8 kn0[4], kn1[4];
    {
      const int kbn = (kt < 24 ? kt + 1 : kt) * 64;
#pragma unroll
      for (int nt = 0; nt < 4; ++nt) {
        int kr = kbn + nt * 16 + l15;
        int krc = kr < NTOK ? kr : NTOK - 1;
        const unsigned short* kp = Kh + hb + (size_t)krc * 64 + l4 * 8;
        kn0[nt] = *(const bf16x8*)kp;
        kn1[nt] = *(const bf16x8*)(kp + 32);
      }
    }

    // ---- S^T = K·Q^T with current K fragments ----
    f32x4 s[4] = {};           // S^T: row key=kb+nt*16+l4*4+r, col qrow=l15
#pragma unroll
    for (int nt = 0; nt < 4; ++nt) {
      s[nt] = __builtin_amdgcn_mfma_f32_16x16x32_bf16(kc0[nt], q0, s[nt], 0, 0, 0);
      s[nt] = __builtin_amdgcn_mfma_f32_16x16x32_bf16(kc1[nt], q1, s[nt], 0, 0, 0);
    }
    if (kb + 64 > NTOK) {      // mask invalid keys (last tile only)
#pragma unroll
      for (int nt = 0; nt < 4; ++nt)
#pragma unroll
        for (int r = 0; r < 4; ++r)
          if (kb + nt * 16 + l4 * 4 + r >= NTOK) s[nt][r] = -1e30f;
    }
    // ---- online softmax: row = fixed l15 -> in-lane reduce + 2 shuffles ----
    float rmax = s[0][0];
#pragma unroll
    for (int nt = 0; nt < 4; ++nt)
#pragma unroll
      for (int r = 0; r < 4; ++r) rmax = fmaxf(rmax, s[nt][r]);
    rmax = fmaxf(rmax, __shfl_xor(rmax, 16));
    rmax = fmaxf(rmax, __shfl_xor(rmax, 32));
    float mn = fmaxf(m, rmax);
    float alpha = __expf(m - mn);
    m = mn;
    float rsum = 0.0f;
#pragma unroll
    for (int nt = 0; nt < 4; ++nt)
#pragma unroll
      for (int r = 0; r < 4; ++r) {
        float p = __expf(s[nt][r] - mn);
        s[nt][r] = p;
        rsum += p;
      }
    rsum += __shfl_xor(rsum, 16);
    rsum += __shfl_xor(rsum, 32);
    l = l * alpha + rsum;
#pragma unroll
    for (int dt = 0; dt < 4; ++dt)
#pragma unroll
      for (int r = 0; r < 4; ++r) oacc[dt][r] *= alpha;   // alpha lane-uniform per qrow

    // ---- P (C/D of S^T) -> P^T B-operand fragments via shuffles ----
    unsigned pk01[4], pk23[4];
#pragma unroll
    for (int nt = 0; nt < 4; ++nt) {
      pk01[nt] = (unsigned)f2b(s[nt][0]) | ((unsigned)f2b(s[nt][1]) << 16);
      pk23[nt] = (unsigned)f2b(s[nt][2]) | ((unsigned)f2b(s[nt][3]) << 16);
    }
    const int srcA = ((l4 & 1) << 5) | l15;   // lane holding keys (l4&1)*8 + {0..3}
    const int srcB = srcA + 16;               // keys (l4&1)*8 + {4..7}
    const bool hi = (l4 >> 1) != 0;           // tile select: nt' = 2kc + (l4>>1)
    union PB { unsigned u[4]; bf16x8 v; } pf[2];
#pragma unroll
    for (int kc = 0; kc < 2; ++kc) {
      unsigned t0, t1;
      t0 = __shfl(pk01[2 * kc], srcA); t1 = __shfl(pk01[2 * kc + 1], srcA);
      pf[kc].u[0] = hi ? t1 : t0;
      t0 = __shfl(pk23[2 * kc], srcA); t1 = __shfl(pk23[2 * kc + 1], srcA);
      pf[kc].u[1] = hi ? t1 : t0;
      t0 = __shfl(pk01[2 * kc], srcB); t1 = __shfl(pk01[2 * kc + 1], srcB);
      pf[kc].u[2] = hi ? t1 : t0;
      t0 = __shfl(pk23[2 * kc], srcB); t1 = __shfl(pk23[2 * kc + 1], srcB);
      pf[kc].u[3] = hi ? t1 : t0;
    }
    // ---- O^T += V^T · P^T ----
#pragma unroll
    for (int dt = 0; dt < 4; ++dt) {
      oacc[dt] = __builtin_amdgcn_mfma_f32_16x16x32_bf16(vf0[dt], pf[0].v, oacc[dt], 0, 0, 0);
      oacc[dt] = __builtin_amdgcn_mfma_f32_16x16x32_bf16(vf1[dt], pf[1].v, oacc[dt], 0, 0, 0);
    }
    // ---- rotate K double buffer ----
#pragma unroll
    for (int nt = 0; nt < 4; ++nt) { kc0[nt] = kn0[nt]; kc1[nt] = kn1[nt]; }
  }

  // epilogue: O^T -> per-wave LDS transpose -> coalesced store in [b][t][h][d] layout
  float inv = 1.0f / l;
#pragma unroll
  for (int dt = 0; dt < 4; ++dt)
#pragma unroll
    for (int r = 0; r < 4; ++r)
      Os[w][l15 * 72 + dt * 16 + l4 * 4 + r] = f2b(oacc[dt][r] * inv);
  // same-wave LDS write->read; compiler inserts lgkmcnt wait
  if (qrow < NTOK) {
    uint4 a  = *(const uint4*)&Os[w][l15 * 72 + l4 * 16];
    uint4 bq = *(const uint4*)&Os[w][l15 * 72 + l4 * 16 + 8];
    unsigned short* op = O + ((size_t)(b * NTOK + qrow)) * HID + head * 64;
    *(uint4*)(op + l4 * 16) = a;
    *(uint4*)(op + l4 * 16 + 8) = bq;
  }
}

// ---------------- host launch ----------------
extern "C" void kernel_launch(void* const* d_in, const int* in_sizes, int n_in,
                              void* d_out, int out_size, void* d_ws, size_t ws_size,
                              hipStream_t stream) {
  (void)in_sizes; (void)n_in; (void)out_size; (void)ws_size;
  const float* pv      = (const float*)d_in[0];
  const float* patch_w = (const float*)d_in[1];
  const float* patch_b = (const float*)d_in[2];
  const float* ln1_g   = (const float*)d_in[3];
  const float* ln1_b   = (const float*)d_in[4];
  const float* qw = (const float*)d_in[5];
  const float* qb = (const float*)d_in[6];
  const float* kw = (const float*)d_in[7];
  const float* kb = (const float*)d_in[8];
  const float* vw = (const float*)d_in[9];
  const float* vb = (const float*)d_in[10];
  const float* pw = (const float*)d_in[11];
  const float* pb = (const float*)d_in[12];
  const float* ln2_g = (const float*)d_in[13];
  const float* ln2_b = (const float*)d_in[14];
  const float* fc1w = (const float*)d_in[15];
  const float* fc1b = (const float*)d_in[16];
  const float* fc2w = (const float*)d_in[17];
  const float* fc2b = (const float*)d_in[18];
  const float* lnf_g = (const float*)d_in[19];
  const float* lnf_b = (const float*)d_in[20];

  char* wsp = (char*)d_ws;
  auto alloc = [&](size_t bytes) {
    char* p = wsp;
    wsp += (bytes + 255) & ~(size_t)255;
    return p;
  };
  unsigned short* wPatch = (unsigned short*)alloc((size_t)1024 * 1536 * 2);
  unsigned short* wQKV   = (unsigned short*)alloc((size_t)NLAYER * 3072 * 1024 * 2);
  unsigned short* wP     = (unsigned short*)alloc((size_t)NLAYER * HID * HID * 2);
  unsigned short* wF1    = (unsigned short*)alloc((size_t)NLAYER * MLPD * HID * 2);
  unsigned short* wF2    = (unsigned short*)alloc((size_t)NLAYER * HID * MLPD * 2);
  float*          qkvbias = (float*)alloc((size_t)NLAYER * 3072 * 4);
  unsigned short* Aim  = (unsigned short*)alloc((size_t)ROWS * CONVK * 2);
  float*          h    = (float*)alloc((size_t)ROWS * HID * 4);
  unsigned short* xnb  = (unsigned short*)alloc((size_t)ROWS * HID * 2);
  unsigned short* qkvo = (unsigned short*)alloc((size_t)ROWS * 3072 * 2);
  unsigned short* Qh   = (unsigned short*)alloc((size_t)ROWS * HID * 2);
  unsigned short* Kh   = (unsigned short*)alloc((size_t)ROWS * HID * 2);
  unsigned short* VT   = (unsigned short*)alloc((size_t)ROWS * HID * 2 + 4096);
  unsigned short* ob   = (unsigned short*)alloc((size_t)ROWS * HID * 2);
  unsigned short* mb   = (unsigned short*)alloc((size_t)ROWS * MLPD * 2);

  auto cast = [&](const float* s, unsigned short* d, long long n) {
    long long n4 = n / 4;
    int grid = (int)((n4 + 255) / 256);
    if (grid > 16384) grid = 16384;
    cast4_k<<<grid, 256, 0, stream>>>(s, d, n4);
  };
  cast(patch_w, wPatch, (long long)1024 * 1536);
  castqkv_k<<<dim3(4096, 3), 256, 0, stream>>>(qw, kw, vw, wQKV);
  cast(pw, wP, (long long)NLAYER * HID * HID);
  cast(fc1w, wF1, (long long)NLAYER * MLPD * HID);
  cast(fc2w, wF2, (long long)NLAYER * HID * MLPD);
  biascat_k<<<48, 256, 0, stream>>>(qb, kb, vb, qkvbias);

  im2col_k<<<(ROWS * CONVK) / 256, 256, 0, stream>>>(pv, Aim);
  gemm_bt<0><<<dim3(HID / 128, (ROWS + 127) / 128), 256, 0, stream>>>(
      Aim, wPatch, patch_b, nullptr, h, nullptr, ROWS, HID, CONVK);

  for (int i = 0; i < NLAYER; ++i) {
    ln_k<1><<<ROWS, 256, 0, stream>>>(h, ln1_g + i * HID, ln1_b + i * HID, xnb, nullptr);
    gemm_bt<2><<<dim3(3072 / 128, (ROWS + 127) / 128), 256, 0, stream>>>(
        xnb, wQKV + (size_t)i * 3072 * 1024, qkvbias + i * 3072, nullptr, nullptr, qkvo,
        ROWS, 3072, HID);
    qkvprep_k<<<dim3(25, 32), 256, 0, stream>>>(qkvo, Qh, Kh, VT);
    flash3_k<<<dim3(32, 25), 256, 0, stream>>>(Qh, Kh, VT, ob);
    gemm_bt<1><<<dim3(HID / 128, (ROWS + 127) / 128), 256, 0, stream>>>(
        ob, wP + (size_t)i * HID * HID, pb + i * HID, h, h, nullptr, ROWS, HID, HID);
    ln_k<1><<<ROWS, 256, 0, stream>>>(h, ln2_g + i * HID, ln2_b + i * HID, xnb, nullptr);
    gemm_bt<3><<<dim3(MLPD / 128, (ROWS + 127) / 128), 256, 0, stream>>>(
        xnb, wF1 + (size_t)i * MLPD * HID, fc1b + i * MLPD, nullptr, nullptr, mb,
        ROWS, MLPD, HID);
    gemm_bt<1><<<dim3(HID / 128, (ROWS + 127) / 128), 256, 0, stream>>>(
        mb, wF2 + (size_t)i * HID * MLPD, fc2b + i * HID, h, h, nullptr, ROWS, HID, MLPD);
  }
  ln_k<0><<<ROWS, 256, 0, stream>>>(h, lnf_g, lnf_b, nullptr, (float*)d_out);
}

// Round 4
// 1682.331 us; speedup vs baseline: 1.1566x; 1.1566x over previous
//
#include <hip/hip_runtime.h>
#include <math.h>

// ---------------- constants ----------------
#define NTOK   1568
#define BATCH  2
#define HID    1024
#define MLPD   4096
#define NLAYER 4
#define ROWS   (BATCH*NTOK)   // 3136
#define CONVK  1536

typedef __bf16 bf16x8 __attribute__((ext_vector_type(8)));
typedef float  f32x4  __attribute__((ext_vector_type(4)));

__device__ __forceinline__ unsigned short f2b(float f) {
  unsigned int u = __float_as_uint(f);
  unsigned int r = u + 0x7FFFu + ((u >> 16) & 1u);   // RNE
  return (unsigned short)(r >> 16);
}
__device__ __forceinline__ float b2f(unsigned short s) {
  return __uint_as_float((unsigned int)s << 16);
}

// async global->LDS 16B; lds ptr must be wave-uniform base (HW adds lane*16)
__device__ __forceinline__ void async16(const unsigned short* g, unsigned short* l) {
  __builtin_amdgcn_global_load_lds(
      (__attribute__((address_space(1))) void*)(void*)g,
      (__attribute__((address_space(3))) void*)(void*)l, 16, 0, 0);
}

// ---------------- fp32 -> bf16 cast (x4 vectorized, grid-stride) ----------------
__global__ __launch_bounds__(256) void cast4_k(const float* __restrict__ s,
                                               unsigned short* __restrict__ d,
                                               long long n4) {
  long long i = (long long)blockIdx.x * 256 + threadIdx.x;
  long long stride = (long long)gridDim.x * 256;
  for (; i < n4; i += stride) {
    float4 v = ((const float4*)s)[i];
    *(ushort4*)(d + i * 4) = make_ushort4(f2b(v.x), f2b(v.y), f2b(v.z), f2b(v.w));
  }
}

// cast q/k/v weights into one concatenated per-layer buffer wQKV[L][3072][1024]
__global__ __launch_bounds__(256) void castqkv_k(const float* __restrict__ q,
                                                 const float* __restrict__ k,
                                                 const float* __restrict__ v,
                                                 unsigned short* __restrict__ dst) {
  const float* src = blockIdx.y == 0 ? q : (blockIdx.y == 1 ? k : v);
  long long i4 = (long long)blockIdx.x * 256 + threadIdx.x;   // exactly L*HH/4
  long long e = i4 * 4;
  int layer = (int)(e >> 20);                                  // HH = 1<<20
  long long de = e + ((long long)(2 * layer + blockIdx.y) << 20);
  float4 val = ((const float4*)src)[i4];
  *(ushort4*)(dst + de) = make_ushort4(f2b(val.x), f2b(val.y), f2b(val.z), f2b(val.w));
}

__global__ __launch_bounds__(256) void biascat_k(const float* __restrict__ qb,
                                                 const float* __restrict__ kb,
                                                 const float* __restrict__ vb,
                                                 float* __restrict__ dst) {
  int idx = blockIdx.x * 256 + threadIdx.x;   // L*3072
  int layer = idx / 3072, c = idx % 3072;
  float v = c < 1024 ? qb[layer * 1024 + c]
            : (c < 2048 ? kb[layer * 1024 + c - 1024] : vb[layer * 1024 + c - 2048]);
  dst[idx] = v;
}

// ---------------- im2col for the tubelet conv ----------------
__global__ __launch_bounds__(256) void im2col_k(const float* __restrict__ pv,
                                                unsigned short* __restrict__ A) {
  int idx = blockIdx.x * 256 + threadIdx.x;       // exactly ROWS*CONVK threads
  int row = idx / CONVK, col = idx % CONVK;
  int b = row / NTOK, t = row % NTOK;
  int d = t / 196, r = t % 196, hh = r / 14, ww = r % 14;
  int c = col >> 9, r2 = col & 511, td = r2 >> 8, ph = (r2 >> 4) & 15, pw = r2 & 15;
  int frame = 2 * d + td;
  const float* src = pv + ((((long long)b * 16 + frame) * 3 + c) * 224 + (hh * 16 + ph)) * 224
                        + (ww * 16 + pw);
  A[idx] = f2b(*src);
}

// ---------------- GEMM: C[M,N] = A[M,K](bf16) * B[N,K]^T(bf16) + bias ----------------
// EPI: 0 = fp32 out; 1 = fp32 out + resid; 2 = bf16 out; 3 = exact-GELU -> bf16 out
template <int EPI>
__global__ __launch_bounds__(256) void gemm_bt(const unsigned short* __restrict__ A,
                                               const unsigned short* __restrict__ B,
                                               const float* __restrict__ bias,
                                               const float* __restrict__ resid,
                                               float* __restrict__ outF,
                                               unsigned short* __restrict__ outB,
                                               int M, int N, int K) {
  __shared__ unsigned short As[128 * 32];
  __shared__ unsigned short Bs[128 * 32];
  const int tid = threadIdx.x;
  const int lane = tid & 63;
  const int w = tid >> 6;
  const int wm = (w >> 1) * 64, wn = (w & 1) * 64;
  const int l15 = lane & 15, l4 = lane >> 4;
  const int bm = blockIdx.y, bn = blockIdx.x;
  const int wbase = tid & ~63;   // wave-uniform

  f32x4 acc[4][4] = {};

  for (int k0 = 0; k0 < K; k0 += 32) {
    __syncthreads();
#pragma unroll
    for (int it = 0; it < 2; ++it) {
      int c = it * 256 + tid;
      int rowA = bm * 128 + (c >> 2);
      if (rowA >= M) rowA = M - 1;
      async16(A + (size_t)rowA * K + k0 + (c & 3) * 8, &As[(it * 256 + wbase) * 8]);
      int rowB = bn * 128 + (c >> 2);
      async16(B + (size_t)rowB * K + k0 + (c & 3) * 8, &Bs[(it * 256 + wbase) * 8]);
    }
    __syncthreads();

    bf16x8 af[4], bfr[4];
#pragma unroll
    for (int i = 0; i < 4; ++i) af[i]  = *(const bf16x8*)&As[(wm + i * 16 + l15) * 32 + l4 * 8];
#pragma unroll
    for (int j = 0; j < 4; ++j) bfr[j] = *(const bf16x8*)&Bs[(wn + j * 16 + l15) * 32 + l4 * 8];
#pragma unroll
    for (int i = 0; i < 4; ++i)
#pragma unroll
      for (int j = 0; j < 4; ++j)
        acc[i][j] = __builtin_amdgcn_mfma_f32_16x16x32_bf16(af[i], bfr[j], acc[i][j], 0, 0, 0);
  }

#pragma unroll
  for (int i = 0; i < 4; ++i) {
    int rowb = bm * 128 + wm + i * 16 + l4 * 4;
#pragma unroll
    for (int r = 0; r < 4; ++r) {
      int rr = rowb + r;
      if (rr >= M) continue;
#pragma unroll
      for (int j = 0; j < 4; ++j) {
        int col = bn * 128 + wn + j * 16 + l15;
        float v = acc[i][j][r] + bias[col];
        size_t o = (size_t)rr * N + col;
        if (EPI == 0) outF[o] = v;
        else if (EPI == 1) outF[o] = v + resid[o];
        else if (EPI == 2) outB[o] = f2b(v);
        else { float ge = 0.5f * v * (1.0f + erff(v * 0.70710678118654752f)); outB[o] = f2b(ge); }
      }
    }
  }
}

// ---------------- LayerNorm (row=1024) ----------------
template <int OUT_BF16>
__global__ __launch_bounds__(256) void ln_k(const float* __restrict__ x,
                                            const float* __restrict__ g,
                                            const float* __restrict__ b,
                                            unsigned short* __restrict__ oB,
                                            float* __restrict__ oF) {
  __shared__ float red[8];
  const int row = blockIdx.x, tid = threadIdx.x;
  const float4 v = ((const float4*)(x + (size_t)row * HID))[tid];
  float s = v.x + v.y + v.z + v.w;
  float q = v.x * v.x + v.y * v.y + v.z * v.z + v.w * v.w;
  for (int off = 32; off; off >>= 1) { s += __shfl_xor(s, off); q += __shfl_xor(q, off); }
  if ((tid & 63) == 0) { red[tid >> 6] = s; red[4 + (tid >> 6)] = q; }
  __syncthreads();
  float ts = red[0] + red[1] + red[2] + red[3];
  float tq = red[4] + red[5] + red[6] + red[7];
  float mu = ts * (1.0f / HID);
  float var = tq * (1.0f / HID) - mu * mu;
  float rs = rsqrtf(var + 1e-6f);
  int col = tid * 4;
  float o0 = (v.x - mu) * rs * g[col + 0] + b[col + 0];
  float o1 = (v.y - mu) * rs * g[col + 1] + b[col + 1];
  float o2 = (v.z - mu) * rs * g[col + 2] + b[col + 2];
  float o3 = (v.w - mu) * rs * g[col + 3] + b[col + 3];
  if (OUT_BF16) {
    *(ushort4*)(oB + (size_t)row * HID + col) = make_ushort4(f2b(o0), f2b(o1), f2b(o2), f2b(o3));
  } else {
    *(float4*)(oF + (size_t)row * HID + col) = make_float4(o0, o1, o2, o3);
  }
}

// ---------------- QKV prep: RoPE(q,k)+scale -> head-major; V -> per-head transposed ----
// grid (25 token-tiles, 32 bh); block 256
__global__ __launch_bounds__(256) void qkvprep_k(const unsigned short* __restrict__ qkvb,
                                                 unsigned short* __restrict__ Qh,
                                                 unsigned short* __restrict__ Kh,
                                                 unsigned short* __restrict__ VT) {
  __shared__ unsigned short Vs[64 * 72];
  const int tile = blockIdx.x, bh = blockIdx.y;
  const int b = bh >> 4, head = bh & 15;
  const int tid = threadIdx.x;
  const int tl = tid >> 2, dc = tid & 3;
  const int tg = tile * 64 + tl;
  const int trc = tg < NTOK ? tg : NTOK - 1;
  const bool valid = tg < NTOK;
  const size_t srow = ((size_t)(b * NTOK + trc)) * 3072 + head * 64 + dc * 16;

  // V chunk -> LDS
  {
    uint4 v0 = *(const uint4*)(qkvb + srow + 2048);
    uint4 v1 = *(const uint4*)(qkvb + srow + 2048 + 8);
    *(uint4*)&Vs[tl * 72 + dc * 16] = v0;
    *(uint4*)&Vs[tl * 72 + dc * 16 + 8] = v1;
  }

  // RoPE on q,k (8 pairs per thread)
  const int t = trc;
  const int dpos = t / 196, rem = t - dpos * 196, hpos = rem / 14, wpos = rem - hpos * 14;
  const float LG = 0.9210340371976184f;  // ln(10000)/10
  union V16 { uint4 u[2]; unsigned short s[16]; };
  V16 qin, kin, qout, kout;
  qin.u[0] = *(const uint4*)(qkvb + srow);
  qin.u[1] = *(const uint4*)(qkvb + srow + 8);
  kin.u[0] = *(const uint4*)(qkvb + srow + 1024);
  kin.u[1] = *(const uint4*)(qkvb + srow + 1024 + 8);
#pragma unroll
  for (int p = 0; p < 8; ++p) {
    int d0 = dc * 16 + 2 * p;
    float qx0 = b2f(qin.s[2 * p]), qx1 = b2f(qin.s[2 * p + 1]);
    float kx0 = b2f(kin.s[2 * p]), kx1 = b2f(kin.s[2 * p + 1]);
    float qo0, qo1, ko0, ko1;
    if (d0 >= 60) { qo0 = qx0; qo1 = qx1; ko0 = kx0; ko1 = kx1; }
    else {
      int region = d0 / 20;
      int j0 = d0 - region * 20;
      int pos = region == 0 ? dpos : (region == 1 ? hpos : wpos);
      float fp = (float)pos;
      int i0 = j0 % 10, i1 = (j0 + 1) % 10;
      float f0 = expf(-LG * (float)i0) * fp;
      float f1 = expf(-LG * (float)i1) * fp;
      float c0 = cosf(f0), s0 = sinf(f0), c1 = cosf(f1), s1 = sinf(f1);
      qo0 = qx0 * c0 - qx1 * s0; qo1 = qx1 * c1 + qx0 * s1;
      ko0 = kx0 * c0 - kx1 * s0; ko1 = kx1 * c1 + kx0 * s1;
    }
    qout.s[2 * p]     = f2b(qo0 * 0.125f);     // fold attention scale into Q
    qout.s[2 * p + 1] = f2b(qo1 * 0.125f);
    kout.s[2 * p]     = f2b(ko0);
    kout.s[2 * p + 1] = f2b(ko1);
  }
  if (valid) {
    size_t drow = ((size_t)bh * NTOK + tg) * 64 + dc * 16;
    *(uint4*)(Qh + drow)     = qout.u[0];
    *(uint4*)(Qh + drow + 8) = qout.u[1];
    *(uint4*)(Kh + drow)     = kout.u[0];
    *(uint4*)(Kh + drow + 8) = kout.u[1];
  }
  __syncthreads();
  // V transpose out: thread = (dim, token-chunk)
  {
    int d = tid >> 2, tc = tid & 3;
    if (tile * 64 + tc * 16 < NTOK) {
      V16 o;
#pragma unroll
      for (int jj = 0; jj < 16; ++jj) o.s[jj] = Vs[(tc * 16 + jj) * 72 + d];
      unsigned short* dst = VT + ((size_t)bh * 64 + d) * NTOK + tile * 64 + tc * 16;
      *(uint4*)dst = o.u[0];
      *(uint4*)(dst + 8) = o.u[1];
    }
  }
}

// ---------------- flash attention v4: async LDS double-buffer, swizzled chunks -------
// S^T = K·Q^T, O^T = V^T·P^T. grid (32 bh, 25 q-tiles), block 256 (4 waves).
// Staging: global_load_lds (unsinkable), chunk order XOR-swizzled so 128B-stride LDS
// rows read conflict-free. One barrier per K-tile; prefetch has a full iteration of
// compute to land before the barrier's vmcnt(0) drain.
__global__ __launch_bounds__(256, 3) void flash4_k(const unsigned short* __restrict__ Qh,
                                                   const unsigned short* __restrict__ Kh,
                                                   const unsigned short* __restrict__ VT,
                                                   unsigned short* __restrict__ O) {
  __shared__ unsigned short Ks[2][64 * 64];
  __shared__ unsigned short Vs[2][64 * 64];
  __shared__ unsigned short Os[4][16 * 72];
  const int bh = blockIdx.x, qt = blockIdx.y;
  const int b = bh >> 4, head = bh & 15;
  const int tid = threadIdx.x, lane = tid & 63, w = tid >> 6;
  const int l15 = lane & 15, l4 = lane >> 4;
  const size_t hb = (size_t)bh * NTOK * 64;
  const unsigned short* kgp = Kh + hb;
  const unsigned short* vbp = VT + (size_t)bh * 64 * NTOK;

  // staging coords: issue it, wave w, lane: row=(it*4+w)*8+(lane>>3), glob chunk=(lane&7)^(row&7)
  const int srow0 = w * 8 + (lane >> 3);          // it=0 row
  const int scg0  = (lane & 7) ^ (srow0 & 7);
  const int srow1 = srow0 + 32;                   // it=1 row
  const int scg1  = (lane & 7) ^ (srow1 & 7);

  const int qrow = qt * 64 + w * 16 + l15;
  const int qrc = qrow < NTOK ? qrow : NTOK - 1;
  bf16x8 q0 = *(const bf16x8*)(Qh + hb + (size_t)qrc * 64 + l4 * 8);
  bf16x8 q1 = *(const bf16x8*)(Qh + hb + (size_t)qrc * 64 + 32 + l4 * 8);

  f32x4 oacc[4] = {};
  float m = -1e30f, l = 0.0f;

  // prologue: stage tile 0 into buffer 0
  {
    async16(kgp + (size_t)srow0 * 64 + scg0 * 8, &Ks[0][(size_t)w * 512]);
    async16(kgp + (size_t)srow1 * 64 + scg1 * 8, &Ks[0][(size_t)(w + 4) * 512]);
    async16(vbp + (size_t)srow0 * NTOK + scg0 * 8, &Vs[0][(size_t)w * 512]);
    async16(vbp + (size_t)srow1 * NTOK + scg1 * 8, &Vs[0][(size_t)(w + 4) * 512]);
  }

  const int h7 = l15 & 7;
  const int p1 = (l4 ^ h7) * 8;          // phys offset of logical chunk l4
  const int p2 = ((l4 + 4) ^ h7) * 8;    // phys offset of logical chunk l4+4

  for (int kt = 0; kt < 25; ++kt) {
    const int cur = kt & 1, nxt = cur ^ 1;
    const int kb = kt * 64;
    __syncthreads();   // vmcnt(0) drain: prefetch from last iter guaranteed landed

    if (kt < 24) {     // stage tile kt+1 into the other buffer (unsinkable async)
      const int kn = kb + 64;
      async16(kgp + (size_t)(kn + srow0) * 64 + scg0 * 8, &Ks[nxt][(size_t)w * 512]);
      async16(kgp + (size_t)(kn + srow1) * 64 + scg1 * 8, &Ks[nxt][(size_t)(w + 4) * 512]);
      async16(vbp + (size_t)srow0 * NTOK + kn + scg0 * 8, &Vs[nxt][(size_t)w * 512]);
      async16(vbp + (size_t)srow1 * NTOK + kn + scg1 * 8, &Vs[nxt][(size_t)(w + 4) * 512]);
    }

    // ---- K fragments from LDS (conflict-free swizzled b128 reads) ----
    bf16x8 kc0[4], kc1[4];
#pragma unroll
    for (int nt = 0; nt < 4; ++nt) {
      const unsigned short* kr = &Ks[cur][(nt * 16 + l15) * 64];
      kc0[nt] = *(const bf16x8*)(kr + p1);
      kc1[nt] = *(const bf16x8*)(kr + p2);
    }
    f32x4 s[4] = {};
#pragma unroll
    for (int nt = 0; nt < 4; ++nt) {
      s[nt] = __builtin_amdgcn_mfma_f32_16x16x32_bf16(kc0[nt], q0, s[nt], 0, 0, 0);
      s[nt] = __builtin_amdgcn_mfma_f32_16x16x32_bf16(kc1[nt], q1, s[nt], 0, 0, 0);
    }
    // ---- V fragments (issued here; consumed after softmax) ----
    bf16x8 vf0[4], vf1[4];
#pragma unroll
    for (int dt = 0; dt < 4; ++dt) {
      const unsigned short* vr = &Vs[cur][(dt * 16 + l15) * 64];
      vf0[dt] = *(const bf16x8*)(vr + p1);
      vf1[dt] = *(const bf16x8*)(vr + p2);
    }

    if (kb + 64 > NTOK) {      // mask invalid keys (last tile only)
#pragma unroll
      for (int nt = 0; nt < 4; ++nt)
#pragma unroll
        for (int r = 0; r < 4; ++r)
          if (kb + nt * 16 + l4 * 4 + r >= NTOK) s[nt][r] = -1e30f;
    }
    // ---- online softmax: row = fixed l15 -> in-lane reduce + 2 shuffles ----
    float rmax = s[0][0];
#pragma unroll
    for (int nt = 0; nt < 4; ++nt)
#pragma unroll
      for (int r = 0; r < 4; ++r) rmax = fmaxf(rmax, s[nt][r]);
    rmax = fmaxf(rmax, __shfl_xor(rmax, 16));
    rmax = fmaxf(rmax, __shfl_xor(rmax, 32));
    float mn = fmaxf(m, rmax);
    float alpha = __expf(m - mn);
    m = mn;
    float rsum = 0.0f;
#pragma unroll
    for (int nt = 0; nt < 4; ++nt)
#pragma unroll
      for (int r = 0; r < 4; ++r) {
        float p = __expf(s[nt][r] - mn);
        s[nt][r] = p;
        rsum += p;
      }
    rsum += __shfl_xor(rsum, 16);
    rsum += __shfl_xor(rsum, 32);
    l = l * alpha + rsum;
#pragma unroll
    for (int dt = 0; dt < 4; ++dt)
#pragma unroll
      for (int r = 0; r < 4; ++r) oacc[dt][r] *= alpha;   // alpha lane-uniform per qrow

    // ---- P (C/D of S^T) -> P^T B-operand fragments via shuffles ----
    unsigned pk01[4], pk23[4];
#pragma unroll
    for (int nt = 0; nt < 4; ++nt) {
      pk01[nt] = (unsigned)f2b(s[nt][0]) | ((unsigned)f2b(s[nt][1]) << 16);
      pk23[nt] = (unsigned)f2b(s[nt][2]) | ((unsigned)f2b(s[nt][3]) << 16);
    }
    const int srcA = ((l4 & 1) << 5) | l15;   // lane holding keys (l4&1)*8 + {0..3}
    const int srcB = srcA + 16;               // keys (l4&1)*8 + {4..7}
    const bool hi = (l4 >> 1) != 0;           // tile select: nt' = 2kc + (l4>>1)
    union PB { unsigned u[4]; bf16x8 v; } pf[2];
#pragma unroll
    for (int kc = 0; kc < 2; ++kc) {
      unsigned t0, t1;
      t0 = __shfl(pk01[2 * kc], srcA); t1 = __shfl(pk01[2 * kc + 1], srcA);
      pf[kc].u[0] = hi ? t1 : t0;
      t0 = __shfl(pk23[2 * kc], srcA); t1 = __shfl(pk23[2 * kc + 1], srcA);
      pf[kc].u[1] = hi ? t1 : t0;
      t0 = __shfl(pk01[2 * kc], srcB); t1 = __shfl(pk01[2 * kc + 1], srcB);
      pf[kc].u[2] = hi ? t1 : t0;
      t0 = __shfl(pk23[2 * kc], srcB); t1 = __shfl(pk23[2 * kc + 1], srcB);
      pf[kc].u[3] = hi ? t1 : t0;
    }
    // ---- O^T += V^T · P^T ----
#pragma unroll
    for (int dt = 0; dt < 4; ++dt) {
      oacc[dt] = __builtin_amdgcn_mfma_f32_16x16x32_bf16(vf0[dt], pf[0].v, oacc[dt], 0, 0, 0);
      oacc[dt] = __builtin_amdgcn_mfma_f32_16x16x32_bf16(vf1[dt], pf[1].v, oacc[dt], 0, 0, 0);
    }
  }

  // epilogue: O^T -> per-wave LDS transpose -> coalesced store in [b][t][h][d] layout
  float inv = 1.0f / l;
#pragma unroll
  for (int dt = 0; dt < 4; ++dt)
#pragma unroll
    for (int r = 0; r < 4; ++r)
      Os[w][l15 * 72 + dt * 16 + l4 * 4 + r] = f2b(oacc[dt][r] * inv);
  // same-wave LDS write->read; compiler inserts lgkmcnt wait
  if (qrow < NTOK) {
    uint4 a  = *(const uint4*)&Os[w][l15 * 72 + l4 * 16];
    uint4 bq = *(const uint4*)&Os[w][l15 * 72 + l4 * 16 + 8];
    unsigned short* op = O + ((size_t)(b * NTOK + qrow)) * HID + head * 64;
    *(uint4*)(op + l4 * 16) = a;
    *(uint4*)(op + l4 * 16 + 8) = bq;
  }
}

// ---------------- host launch ----------------
extern "C" void kernel_launch(void* const* d_in, const int* in_sizes, int n_in,
                              void* d_out, int out_size, void* d_ws, size_t ws_size,
                              hipStream_t stream) {
  (void)in_sizes; (void)n_in; (void)out_size; (void)ws_size;
  const float* pv      = (const float*)d_in[0];
  const float* patch_w = (const float*)d_in[1];
  const float* patch_b = (const float*)d_in[2];
  const float* ln1_g   = (const float*)d_in[3];
  const float* ln1_b   = (const float*)d_in[4];
  const float* qw = (const float*)d_in[5];
  const float* qb = (const float*)d_in[6];
  const float* kw = (const float*)d_in[7];
  const float* kb = (const float*)d_in[8];
  const float* vw = (const float*)d_in[9];
  const float* vb = (const float*)d_in[10];
  const float* pw = (const float*)d_in[11];
  const float* pb = (const float*)d_in[12];
  const float* ln2_g = (const float*)d_in[13];
  const float* ln2_b = (const float*)d_in[14];
  const float* fc1w = (const float*)d_in[15];
  const float* fc1b = (const float*)d_in[16];
  const float* fc2w = (const float*)d_in[17];
  const float* fc2b = (const float*)d_in[18];
  const float* lnf_g = (const float*)d_in[19];
  const float* lnf_b = (const float*)d_in[20];

  char* wsp = (char*)d_ws;
  auto alloc = [&](size_t bytes) {
    char* p = wsp;
    wsp += (bytes + 255) & ~(size_t)255;
    return p;
  };
  unsigned short* wPatch = (unsigned short*)alloc((size_t)1024 * 1536 * 2);
  unsigned short* wQKV   = (unsigned short*)alloc((size_t)NLAYER * 3072 * 1024 * 2);
  unsigned short* wP     = (unsigned short*)alloc((size_t)NLAYER * HID * HID * 2);
  unsigned short* wF1    = (unsigned short*)alloc((size_t)NLAYER * MLPD * HID * 2);
  unsigned short* wF2    = (unsigned short*)alloc((size_t)NLAYER * HID * MLPD * 2);
  float*          qkvbias = (float*)alloc((size_t)NLAYER * 3072 * 4);
  unsigned short* Aim  = (unsigned short*)alloc((size_t)ROWS * CONVK * 2);
  float*          h    = (float*)alloc((size_t)ROWS * HID * 4);
  unsigned short* xnb  = (unsigned short*)alloc((size_t)ROWS * HID * 2);
  unsigned short* qkvo = (unsigned short*)alloc((size_t)ROWS * 3072 * 2);
  unsigned short* Qh   = (unsigned short*)alloc((size_t)ROWS * HID * 2 + 8192);
  unsigned short* Kh   = (unsigned short*)alloc((size_t)ROWS * HID * 2 + 8192);
  unsigned short* VT   = (unsigned short*)alloc((size_t)ROWS * HID * 2 + 8192);
  unsigned short* ob   = (unsigned short*)alloc((size_t)ROWS * HID * 2);
  unsigned short* mb   = (unsigned short*)alloc((size_t)ROWS * MLPD * 2);

  auto cast = [&](const float* s, unsigned short* d, long long n) {
    long long n4 = n / 4;
    int grid = (int)((n4 + 255) / 256);
    if (grid > 16384) grid = 16384;
    cast4_k<<<grid, 256, 0, stream>>>(s, d, n4);
  };
  cast(patch_w, wPatch, (long long)1024 * 1536);
  castqkv_k<<<dim3(4096, 3), 256, 0, stream>>>(qw, kw, vw, wQKV);
  cast(pw, wP, (long long)NLAYER * HID * HID);
  cast(fc1w, wF1, (long long)NLAYER * MLPD * HID);
  cast(fc2w, wF2, (long long)NLAYER * HID * MLPD);
  biascat_k<<<48, 256, 0, stream>>>(qb, kb, vb, qkvbias);

  im2col_k<<<(ROWS * CONVK) / 256, 256, 0, stream>>>(pv, Aim);
  gemm_bt<0><<<dim3(HID / 128, (ROWS + 127) / 128), 256, 0, stream>>>(
      Aim, wPatch, patch_b, nullptr, h, nullptr, ROWS, HID, CONVK);

  for (int i = 0; i < NLAYER; ++i) {
    ln_k<1><<<ROWS, 256, 0, stream>>>(h, ln1_g + i * HID, ln1_b + i * HID, xnb, nullptr);
    gemm_bt<2><<<dim3(3072 / 128, (ROWS + 127) / 128), 256, 0, stream>>>(
        xnb, wQKV + (size_t)i * 3072 * 1024, qkvbias + i * 3072, nullptr, nullptr, qkvo,
        ROWS, 3072, HID);
    qkvprep_k<<<dim3(25, 32), 256, 0, stream>>>(qkvo, Qh, Kh, VT);
    flash4_k<<<dim3(32, 25), 256, 0, stream>>>(Qh, Kh, VT, ob);
    gemm_bt<1><<<dim3(HID / 128, (ROWS + 127) / 128), 256, 0, stream>>>(
        ob, wP + (size_t)i * HID * HID, pb + i * HID, h, h, nullptr, ROWS, HID, HID);
    ln_k<1><<<ROWS, 256, 0, stream>>>(h, ln2_g + i * HID, ln2_b + i * HID, xnb, nullptr);
    gemm_bt<3><<<dim3(MLPD / 128, (ROWS + 127) / 128), 256, 0, stream>>>(
        xnb, wF1 + (size_t)i * MLPD * HID, fc1b + i * MLPD, nullptr, nullptr, mb,
        ROWS, MLPD, HID);
    gemm_bt<1><<<dim3(HID / 128, (ROWS + 127) / 128), 256, 0, stream>>>(
        mb, wF2 + (size_t)i * HID * MLPD, fc2b + i * HID, h, h, nullptr, ROWS, HID, MLPD);
  }
  ln_k<0><<<ROWS, 256, 0, stream>>>(h, lnf_g, lnf_b, nullptr, (float*)d_out);
}

// Round 5
// 1487.798 us; speedup vs baseline: 1.3078x; 1.1308x over previous
//
#include <hip/hip_runtime.h>
#include <math.h>

// ---------------- constants ----------------
#define NTOK   1568
#define BATCH  2
#define HID    1024
#define MLPD   4096
#define NLAYER 4
#define ROWS   (BATCH*NTOK)   // 3136
#define CONVK  1536

typedef __bf16 bf16x8 __attribute__((ext_vector_type(8)));
typedef float  f32x4  __attribute__((ext_vector_type(4)));

__device__ __forceinline__ unsigned short f2b(float f) {
  unsigned int u = __float_as_uint(f);
  unsigned int r = u + 0x7FFFu + ((u >> 16) & 1u);   // RNE
  return (unsigned short)(r >> 16);
}
__device__ __forceinline__ float b2f(unsigned short s) {
  return __uint_as_float((unsigned int)s << 16);
}

// async global->LDS 16B; lds ptr must be wave-uniform base (HW adds lane*16)
__device__ __forceinline__ void async16(const unsigned short* g, unsigned short* l) {
  __builtin_amdgcn_global_load_lds(
      (__attribute__((address_space(1))) void*)(void*)g,
      (__attribute__((address_space(3))) void*)(void*)l, 16, 0, 0);
}

// ---------------- fp32 -> bf16 cast (x4 vectorized, grid-stride) ----------------
__global__ __launch_bounds__(256) void cast4_k(const float* __restrict__ s,
                                               unsigned short* __restrict__ d,
                                               long long n4) {
  long long i = (long long)blockIdx.x * 256 + threadIdx.x;
  long long stride = (long long)gridDim.x * 256;
  for (; i < n4; i += stride) {
    float4 v = ((const float4*)s)[i];
    *(ushort4*)(d + i * 4) = make_ushort4(f2b(v.x), f2b(v.y), f2b(v.z), f2b(v.w));
  }
}

// cast q/k/v weights into one concatenated per-layer buffer wQKV[L][3072][1024]
__global__ __launch_bounds__(256) void castqkv_k(const float* __restrict__ q,
                                                 const float* __restrict__ k,
                                                 const float* __restrict__ v,
                                                 unsigned short* __restrict__ dst) {
  const float* src = blockIdx.y == 0 ? q : (blockIdx.y == 1 ? k : v);
  long long i4 = (long long)blockIdx.x * 256 + threadIdx.x;   // exactly L*HH/4
  long long e = i4 * 4;
  int layer = (int)(e >> 20);                                  // HH = 1<<20
  long long de = e + ((long long)(2 * layer + blockIdx.y) << 20);
  float4 val = ((const float4*)src)[i4];
  *(ushort4*)(dst + de) = make_ushort4(f2b(val.x), f2b(val.y), f2b(val.z), f2b(val.w));
}

__global__ __launch_bounds__(256) void biascat_k(const float* __restrict__ qb,
                                                 const float* __restrict__ kb,
                                                 const float* __restrict__ vb,
                                                 float* __restrict__ dst) {
  int idx = blockIdx.x * 256 + threadIdx.x;   // L*3072
  int layer = idx / 3072, c = idx % 3072;
  float v = c < 1024 ? qb[layer * 1024 + c]
            : (c < 2048 ? kb[layer * 1024 + c - 1024] : vb[layer * 1024 + c - 2048]);
  dst[idx] = v;
}

// ---------------- im2col for the tubelet conv ----------------
__global__ __launch_bounds__(256) void im2col_k(const float* __restrict__ pv,
                                                unsigned short* __restrict__ A) {
  int idx = blockIdx.x * 256 + threadIdx.x;       // exactly ROWS*CONVK threads
  int row = idx / CONVK, col = idx % CONVK;
  int b = row / NTOK, t = row % NTOK;
  int d = t / 196, r = t % 196, hh = r / 14, ww = r % 14;
  int c = col >> 9, r2 = col & 511, td = r2 >> 8, ph = (r2 >> 4) & 15, pw = r2 & 15;
  int frame = 2 * d + td;
  const float* src = pv + ((((long long)b * 16 + frame) * 3 + c) * 224 + (hh * 16 + ph)) * 224
                        + (ww * 16 + pw);
  A[idx] = f2b(*src);
}

// ---------------- GEMM: C[M,N] = A[M,K](bf16) * B[N,K]^T(bf16) ----------------
// Double-buffered LDS (flash4-style: 1 barrier/iter, stage kt+1 then compute kt).
// blockIdx.z selects K-chunk [z*kChunk, (z+1)*kChunk) for split-K.
// EPI: 2 = bias -> bf16 out; 3 = bias+exact-GELU -> bf16 out; 4 = fp32 partial (no bias)
template <int EPI>
__global__ __launch_bounds__(256) void gemm_bt(const unsigned short* __restrict__ A,
                                               const unsigned short* __restrict__ B,
                                               const float* __restrict__ bias,
                                               float* __restrict__ outF,
                                               unsigned short* __restrict__ outB,
                                               int M, int N, int K, int kChunk) {
  __shared__ unsigned short As[2][128 * 32];
  __shared__ unsigned short Bs[2][128 * 32];
  const int tid = threadIdx.x;
  const int lane = tid & 63;
  const int w = tid >> 6;
  const int wm = (w >> 1) * 64, wn = (w & 1) * 64;
  const int l15 = lane & 15, l4 = lane >> 4;
  const int bm = blockIdx.y, bn = blockIdx.x;
  const int wbase = tid & ~63;   // wave-uniform
  const int kbeg = blockIdx.z * kChunk;

  auto stage = [&](int buf, int k0) {
#pragma unroll
    for (int it = 0; it < 2; ++it) {
      int c = it * 256 + tid;
      int rowA = bm * 128 + (c >> 2);
      if (rowA >= M) rowA = M - 1;
      async16(A + (size_t)rowA * K + k0 + (c & 3) * 8, &As[buf][(it * 256 + wbase) * 8]);
      int rowB = bn * 128 + (c >> 2);
      async16(B + (size_t)rowB * K + k0 + (c & 3) * 8, &Bs[buf][(it * 256 + wbase) * 8]);
    }
  };

  f32x4 acc[4][4] = {};
  stage(0, kbeg);
  const int nIter = kChunk >> 5;

  for (int i = 0; i < nIter; ++i) {
    const int cur = i & 1;
    __syncthreads();               // drains stage(cur) issued one compute-phase ago
    if (i + 1 < nIter) stage(cur ^ 1, kbeg + (i + 1) * 32);

    bf16x8 af[4], bfr[4];
#pragma unroll
    for (int ii = 0; ii < 4; ++ii)
      af[ii] = *(const bf16x8*)&As[cur][(wm + ii * 16 + l15) * 32 + l4 * 8];
#pragma unroll
    for (int j = 0; j < 4; ++j)
      bfr[j] = *(const bf16x8*)&Bs[cur][(wn + j * 16 + l15) * 32 + l4 * 8];
#pragma unroll
    for (int ii = 0; ii < 4; ++ii)
#pragma unroll
      for (int j = 0; j < 4; ++j)
        acc[ii][j] = __builtin_amdgcn_mfma_f32_16x16x32_bf16(af[ii], bfr[j], acc[ii][j], 0, 0, 0);
  }

  float* pout = (EPI == 4) ? outF + (size_t)blockIdx.z * ((size_t)M * N) : outF;
#pragma unroll
  for (int ii = 0; ii < 4; ++ii) {
    int rowb = bm * 128 + wm + ii * 16 + l4 * 4;
#pragma unroll
    for (int r = 0; r < 4; ++r) {
      int rr = rowb + r;
      if (rr >= M) continue;
#pragma unroll
      for (int j = 0; j < 4; ++j) {
        int col = bn * 128 + wn + j * 16 + l15;
        size_t o = (size_t)rr * N + col;
        if (EPI == 4) {
          pout[o] = acc[ii][j][r];
        } else {
          float v = acc[ii][j][r] + bias[col];
          if (EPI == 2) outB[o] = f2b(v);
          else { float ge = 0.5f * v * (1.0f + erff(v * 0.70710678118654752f)); outB[o] = f2b(ge); }
        }
      }
    }
  }
}

// ---------------- split-K reduce: out = p0 + p1 + bias (+ resid), fp32 ----------------
template <int HASRESID>
__global__ __launch_bounds__(256) void reduce2_k(const float* __restrict__ p,
                                                 const float* __restrict__ bias,
                                                 const float* __restrict__ resid,
                                                 float* __restrict__ out, int MN) {
  int i4 = blockIdx.x * 256 + threadIdx.x;   // exactly MN/4 threads
  int e = i4 * 4;
  float4 a = ((const float4*)p)[i4];
  float4 b = ((const float4*)(p + MN))[i4];
  int col = e & (HID - 1);                   // N == 1024 for all split-K GEMMs
  float4 bs = *(const float4*)(bias + col);
  float4 v = make_float4(a.x + b.x + bs.x, a.y + b.y + bs.y,
                         a.z + b.z + bs.z, a.w + b.w + bs.w);
  if (HASRESID) {
    float4 r = ((const float4*)resid)[i4];
    v.x += r.x; v.y += r.y; v.z += r.z; v.w += r.w;
  }
  ((float4*)out)[i4] = v;
}

// ---------------- LayerNorm (row=1024) ----------------
template <int OUT_BF16>
__global__ __launch_bounds__(256) void ln_k(const float* __restrict__ x,
                                            const float* __restrict__ g,
                                            const float* __restrict__ b,
                                            unsigned short* __restrict__ oB,
                                            float* __restrict__ oF) {
  __shared__ float red[8];
  const int row = blockIdx.x, tid = threadIdx.x;
  const float4 v = ((const float4*)(x + (size_t)row * HID))[tid];
  float s = v.x + v.y + v.z + v.w;
  float q = v.x * v.x + v.y * v.y + v.z * v.z + v.w * v.w;
  for (int off = 32; off; off >>= 1) { s += __shfl_xor(s, off); q += __shfl_xor(q, off); }
  if ((tid & 63) == 0) { red[tid >> 6] = s; red[4 + (tid >> 6)] = q; }
  __syncthreads();
  float ts = red[0] + red[1] + red[2] + red[3];
  float tq = red[4] + red[5] + red[6] + red[7];
  float mu = ts * (1.0f / HID);
  float var = tq * (1.0f / HID) - mu * mu;
  float rs = rsqrtf(var + 1e-6f);
  int col = tid * 4;
  float o0 = (v.x - mu) * rs * g[col + 0] + b[col + 0];
  float o1 = (v.y - mu) * rs * g[col + 1] + b[col + 1];
  float o2 = (v.z - mu) * rs * g[col + 2] + b[col + 2];
  float o3 = (v.w - mu) * rs * g[col + 3] + b[col + 3];
  if (OUT_BF16) {
    *(ushort4*)(oB + (size_t)row * HID + col) = make_ushort4(f2b(o0), f2b(o1), f2b(o2), f2b(o3));
  } else {
    *(float4*)(oF + (size_t)row * HID + col) = make_float4(o0, o1, o2, o3);
  }
}

// ---------------- QKV prep: RoPE(q,k)+scale -> head-major; V -> per-head transposed ----
// grid (25 token-tiles, 32 bh); block 256
__global__ __launch_bounds__(256) void qkvprep_k(const unsigned short* __restrict__ qkvb,
                                                 unsigned short* __restrict__ Qh,
                                                 unsigned short* __restrict__ Kh,
                                                 unsigned short* __restrict__ VT) {
  __shared__ unsigned short Vs[64 * 72];
  const int tile = blockIdx.x, bh = blockIdx.y;
  const int b = bh >> 4, head = bh & 15;
  const int tid = threadIdx.x;
  const int tl = tid >> 2, dc = tid & 3;
  const int tg = tile * 64 + tl;
  const int trc = tg < NTOK ? tg : NTOK - 1;
  const bool valid = tg < NTOK;
  const size_t srow = ((size_t)(b * NTOK + trc)) * 3072 + head * 64 + dc * 16;

  // V chunk -> LDS
  {
    uint4 v0 = *(const uint4*)(qkvb + srow + 2048);
    uint4 v1 = *(const uint4*)(qkvb + srow + 2048 + 8);
    *(uint4*)&Vs[tl * 72 + dc * 16] = v0;
    *(uint4*)&Vs[tl * 72 + dc * 16 + 8] = v1;
  }

  // RoPE on q,k (8 pairs per thread)
  const int t = trc;
  const int dpos = t / 196, rem = t - dpos * 196, hpos = rem / 14, wpos = rem - hpos * 14;
  const float LG = 0.9210340371976184f;  // ln(10000)/10
  union V16 { uint4 u[2]; unsigned short s[16]; };
  V16 qin, kin, qout, kout;
  qin.u[0] = *(const uint4*)(qkvb + srow);
  qin.u[1] = *(const uint4*)(qkvb + srow + 8);
  kin.u[0] = *(const uint4*)(qkvb + srow + 1024);
  kin.u[1] = *(const uint4*)(qkvb + srow + 1024 + 8);
#pragma unroll
  for (int p = 0; p < 8; ++p) {
    int d0 = dc * 16 + 2 * p;
    float qx0 = b2f(qin.s[2 * p]), qx1 = b2f(qin.s[2 * p + 1]);
    float kx0 = b2f(kin.s[2 * p]), kx1 = b2f(kin.s[2 * p + 1]);
    float qo0, qo1, ko0, ko1;
    if (d0 >= 60) { qo0 = qx0; qo1 = qx1; ko0 = kx0; ko1 = kx1; }
    else {
      int region = d0 / 20;
      int j0 = d0 - region * 20;
      int pos = region == 0 ? dpos : (region == 1 ? hpos : wpos);
      float fp = (float)pos;
      int i0 = j0 % 10, i1 = (j0 + 1) % 10;
      float f0 = expf(-LG * (float)i0) * fp;
      float f1 = expf(-LG * (float)i1) * fp;
      float c0 = cosf(f0), s0 = sinf(f0), c1 = cosf(f1), s1 = sinf(f1);
      qo0 = qx0 * c0 - qx1 * s0; qo1 = qx1 * c1 + qx0 * s1;
      ko0 = kx0 * c0 - kx1 * s0; ko1 = kx1 * c1 + kx0 * s1;
    }
    qout.s[2 * p]     = f2b(qo0 * 0.125f);     // fold attention scale into Q
    qout.s[2 * p + 1] = f2b(qo1 * 0.125f);
    kout.s[2 * p]     = f2b(ko0);
    kout.s[2 * p + 1] = f2b(ko1);
  }
  if (valid) {
    size_t drow = ((size_t)bh * NTOK + tg) * 64 + dc * 16;
    *(uint4*)(Qh + drow)     = qout.u[0];
    *(uint4*)(Qh + drow + 8) = qout.u[1];
    *(uint4*)(Kh + drow)     = kout.u[0];
    *(uint4*)(Kh + drow + 8) = kout.u[1];
  }
  __syncthreads();
  // V transpose out: thread = (dim, token-chunk)
  {
    int d = tid >> 2, tc = tid & 3;
    if (tile * 64 + tc * 16 < NTOK) {
      V16 o;
#pragma unroll
      for (int jj = 0; jj < 16; ++jj) o.s[jj] = Vs[(tc * 16 + jj) * 72 + d];
      unsigned short* dst = VT + ((size_t)bh * 64 + d) * NTOK + tile * 64 + tc * 16;
      *(uint4*)dst = o.u[0];
      *(uint4*)(dst + 8) = o.u[1];
    }
  }
}

// ---------------- flash attention v4: async LDS double-buffer, swizzled chunks -------
__global__ __launch_bounds__(256, 3) void flash4_k(const unsigned short* __restrict__ Qh,
                                                   const unsigned short* __restrict__ Kh,
                                                   const unsigned short* __restrict__ VT,
                                                   unsigned short* __restrict__ O) {
  __shared__ unsigned short Ks[2][64 * 64];
  __shared__ unsigned short Vs[2][64 * 64];
  __shared__ unsigned short Os[4][16 * 72];
  const int bh = blockIdx.x, qt = blockIdx.y;
  const int b = bh >> 4, head = bh & 15;
  const int tid = threadIdx.x, lane = tid & 63, w = tid >> 6;
  const int l15 = lane & 15, l4 = lane >> 4;
  const size_t hb = (size_t)bh * NTOK * 64;
  const unsigned short* kgp = Kh + hb;
  const unsigned short* vbp = VT + (size_t)bh * 64 * NTOK;

  const int srow0 = w * 8 + (lane >> 3);          // it=0 row
  const int scg0  = (lane & 7) ^ (srow0 & 7);
  const int srow1 = srow0 + 32;                   // it=1 row
  const int scg1  = (lane & 7) ^ (srow1 & 7);

  const int qrow = qt * 64 + w * 16 + l15;
  const int qrc = qrow < NTOK ? qrow : NTOK - 1;
  bf16x8 q0 = *(const bf16x8*)(Qh + hb + (size_t)qrc * 64 + l4 * 8);
  bf16x8 q1 = *(const bf16x8*)(Qh + hb + (size_t)qrc * 64 + 32 + l4 * 8);

  f32x4 oacc[4] = {};
  float m = -1e30f, l = 0.0f;

  {
    async16(kgp + (size_t)srow0 * 64 + scg0 * 8, &Ks[0][(size_t)w * 512]);
    async16(kgp + (size_t)srow1 * 64 + scg1 * 8, &Ks[0][(size_t)(w + 4) * 512]);
    async16(vbp + (size_t)srow0 * NTOK + scg0 * 8, &Vs[0][(size_t)w * 512]);
    async16(vbp + (size_t)srow1 * NTOK + scg1 * 8, &Vs[0][(size_t)(w + 4) * 512]);
  }

  const int h7 = l15 & 7;
  const int p1 = (l4 ^ h7) * 8;          // phys offset of logical chunk l4
  const int p2 = ((l4 + 4) ^ h7) * 8;    // phys offset of logical chunk l4+4

  for (int kt = 0; kt < 25; ++kt) {
    const int cur = kt & 1, nxt = cur ^ 1;
    const int kb = kt * 64;
    __syncthreads();   // vmcnt(0) drain: prefetch from last iter guaranteed landed

    if (kt < 24) {
      const int kn = kb + 64;
      async16(kgp + (size_t)(kn + srow0) * 64 + scg0 * 8, &Ks[nxt][(size_t)w * 512]);
      async16(kgp + (size_t)(kn + srow1) * 64 + scg1 * 8, &Ks[nxt][(size_t)(w + 4) * 512]);
      async16(vbp + (size_t)srow0 * NTOK + kn + scg0 * 8, &Vs[nxt][(size_t)w * 512]);
      async16(vbp + (size_t)srow1 * NTOK + kn + scg1 * 8, &Vs[nxt][(size_t)(w + 4) * 512]);
    }

    bf16x8 kc0[4], kc1[4];
#pragma unroll
    for (int nt = 0; nt < 4; ++nt) {
      const unsigned short* kr = &Ks[cur][(nt * 16 + l15) * 64];
      kc0[nt] = *(const bf16x8*)(kr + p1);
      kc1[nt] = *(const bf16x8*)(kr + p2);
    }
    f32x4 s[4] = {};
#pragma unroll
    for (int nt = 0; nt < 4; ++nt) {
      s[nt] = __builtin_amdgcn_mfma_f32_16x16x32_bf16(kc0[nt], q0, s[nt], 0, 0, 0);
      s[nt] = __builtin_amdgcn_mfma_f32_16x16x32_bf16(kc1[nt], q1, s[nt], 0, 0, 0);
    }
    bf16x8 vf0[4], vf1[4];
#pragma unroll
    for (int dt = 0; dt < 4; ++dt) {
      const unsigned short* vr = &Vs[cur][(dt * 16 + l15) * 64];
      vf0[dt] = *(const bf16x8*)(vr + p1);
      vf1[dt] = *(const bf16x8*)(vr + p2);
    }

    if (kb + 64 > NTOK) {
#pragma unroll
      for (int nt = 0; nt < 4; ++nt)
#pragma unroll
        for (int r = 0; r < 4; ++r)
          if (kb + nt * 16 + l4 * 4 + r >= NTOK) s[nt][r] = -1e30f;
    }
    float rmax = s[0][0];
#pragma unroll
    for (int nt = 0; nt < 4; ++nt)
#pragma unroll
      for (int r = 0; r < 4; ++r) rmax = fmaxf(rmax, s[nt][r]);
    rmax = fmaxf(rmax, __shfl_xor(rmax, 16));
    rmax = fmaxf(rmax, __shfl_xor(rmax, 32));
    float mn = fmaxf(m, rmax);
    float alpha = __expf(m - mn);
    m = mn;
    float rsum = 0.0f;
#pragma unroll
    for (int nt = 0; nt < 4; ++nt)
#pragma unroll
      for (int r = 0; r < 4; ++r) {
        float p = __expf(s[nt][r] - mn);
        s[nt][r] = p;
        rsum += p;
      }
    rsum += __shfl_xor(rsum, 16);
    rsum += __shfl_xor(rsum, 32);
    l = l * alpha + rsum;
#pragma unroll
    for (int dt = 0; dt < 4; ++dt)
#pragma unroll
      for (int r = 0; r < 4; ++r) oacc[dt][r] *= alpha;

    unsigned pk01[4], pk23[4];
#pragma unroll
    for (int nt = 0; nt < 4; ++nt) {
      pk01[nt] = (unsigned)f2b(s[nt][0]) | ((unsigned)f2b(s[nt][1]) << 16);
      pk23[nt] = (unsigned)f2b(s[nt][2]) | ((unsigned)f2b(s[nt][3]) << 16);
    }
    const int srcA = ((l4 & 1) << 5) | l15;
    const int srcB = srcA + 16;
    const bool hi = (l4 >> 1) != 0;
    union PB { unsigned u[4]; bf16x8 v; } pf[2];
#pragma unroll
    for (int kc = 0; kc < 2; ++kc) {
      unsigned t0, t1;
      t0 = __shfl(pk01[2 * kc], srcA); t1 = __shfl(pk01[2 * kc + 1], srcA);
      pf[kc].u[0] = hi ? t1 : t0;
      t0 = __shfl(pk23[2 * kc], srcA); t1 = __shfl(pk23[2 * kc + 1], srcA);
      pf[kc].u[1] = hi ? t1 : t0;
      t0 = __shfl(pk01[2 * kc], srcB); t1 = __shfl(pk01[2 * kc + 1], srcB);
      pf[kc].u[2] = hi ? t1 : t0;
      t0 = __shfl(pk23[2 * kc], srcB); t1 = __shfl(pk23[2 * kc + 1], srcB);
      pf[kc].u[3] = hi ? t1 : t0;
    }
#pragma unroll
    for (int dt = 0; dt < 4; ++dt) {
      oacc[dt] = __builtin_amdgcn_mfma_f32_16x16x32_bf16(vf0[dt], pf[0].v, oacc[dt], 0, 0, 0);
      oacc[dt] = __builtin_amdgcn_mfma_f32_16x16x32_bf16(vf1[dt], pf[1].v, oacc[dt], 0, 0, 0);
    }
  }

  float inv = 1.0f / l;
#pragma unroll
  for (int dt = 0; dt < 4; ++dt)
#pragma unroll
    for (int r = 0; r < 4; ++r)
      Os[w][l15 * 72 + dt * 16 + l4 * 4 + r] = f2b(oacc[dt][r] * inv);
  if (qrow < NTOK) {
    uint4 a  = *(const uint4*)&Os[w][l15 * 72 + l4 * 16];
    uint4 bq = *(const uint4*)&Os[w][l15 * 72 + l4 * 16 + 8];
    unsigned short* op = O + ((size_t)(b * NTOK + qrow)) * HID + head * 64;
    *(uint4*)(op + l4 * 16) = a;
    *(uint4*)(op + l4 * 16 + 8) = bq;
  }
}

// ---------------- host launch ----------------
extern "C" void kernel_launch(void* const* d_in, const int* in_sizes, int n_in,
                              void* d_out, int out_size, void* d_ws, size_t ws_size,
                              hipStream_t stream) {
  (void)in_sizes; (void)n_in; (void)out_size; (void)ws_size;
  const float* pv      = (const float*)d_in[0];
  const float* patch_w = (const float*)d_in[1];
  const float* patch_b = (const float*)d_in[2];
  const float* ln1_g   = (const float*)d_in[3];
  const float* ln1_b   = (const float*)d_in[4];
  const float* qw = (const float*)d_in[5];
  const float* qb = (const float*)d_in[6];
  const float* kw = (const float*)d_in[7];
  const float* kb = (const float*)d_in[8];
  const float* vw = (const float*)d_in[9];
  const float* vb = (const float*)d_in[10];
  const float* pw = (const float*)d_in[11];
  const float* pb = (const float*)d_in[12];
  const float* ln2_g = (const float*)d_in[13];
  const float* ln2_b = (const float*)d_in[14];
  const float* fc1w = (const float*)d_in[15];
  const float* fc1b = (const float*)d_in[16];
  const float* fc2w = (const float*)d_in[17];
  const float* fc2b = (const float*)d_in[18];
  const float* lnf_g = (const float*)d_in[19];
  const float* lnf_b = (const float*)d_in[20];

  char* wsp = (char*)d_ws;
  auto alloc = [&](size_t bytes) {
    char* p = wsp;
    wsp += (bytes + 255) & ~(size_t)255;
    return p;
  };
  unsigned short* wPatch = (unsigned short*)alloc((size_t)1024 * 1536 * 2);
  unsigned short* wQKV   = (unsigned short*)alloc((size_t)NLAYER * 3072 * 1024 * 2);
  unsigned short* wP     = (unsigned short*)alloc((size_t)NLAYER * HID * HID * 2);
  unsigned short* wF1    = (unsigned short*)alloc((size_t)NLAYER * MLPD * HID * 2);
  unsigned short* wF2    = (unsigned short*)alloc((size_t)NLAYER * HID * MLPD * 2);
  float*          qkvbias = (float*)alloc((size_t)NLAYER * 3072 * 4);
  unsigned short* Aim  = (unsigned short*)alloc((size_t)ROWS * CONVK * 2);
  float*          h    = (float*)alloc((size_t)ROWS * HID * 4);
  unsigned short* xnb  = (unsigned short*)alloc((size_t)ROWS * HID * 2);   // }
  unsigned short* qkvo = (unsigned short*)alloc((size_t)ROWS * 3072 * 2);  // } contiguous 25.7MB:
  float*          part = (float*)xnb;  // 2 fp32 split-K partials alias xnb+qkvo (both dead then)
  unsigned short* Qh   = (unsigned short*)alloc((size_t)ROWS * HID * 2 + 8192);
  unsigned short* Kh   = (unsigned short*)alloc((size_t)ROWS * HID * 2 + 8192);
  unsigned short* VT   = (unsigned short*)alloc((size_t)ROWS * HID * 2 + 8192);
  unsigned short* ob   = (unsigned short*)alloc((size_t)ROWS * HID * 2);
  unsigned short* mb   = (unsigned short*)alloc((size_t)ROWS * MLPD * 2);

  const int MN = ROWS * HID;            // 3.2M
  const int redGrid = MN / 4 / 256;     // 3136

  auto cast = [&](const float* s, unsigned short* d, long long n) {
    long long n4 = n / 4;
    int grid = (int)((n4 + 255) / 256);
    if (grid > 16384) grid = 16384;
    cast4_k<<<grid, 256, 0, stream>>>(s, d, n4);
  };
  cast(patch_w, wPatch, (long long)1024 * 1536);
  castqkv_k<<<dim3(4096, 3), 256, 0, stream>>>(qw, kw, vw, wQKV);
  cast(pw, wP, (long long)NLAYER * HID * HID);
  cast(fc1w, wF1, (long long)NLAYER * MLPD * HID);
  cast(fc2w, wF2, (long long)NLAYER * HID * MLPD);
  biascat_k<<<48, 256, 0, stream>>>(qb, kb, vb, qkvbias);

  im2col_k<<<(ROWS * CONVK) / 256, 256, 0, stream>>>(pv, Aim);
  // conv as GEMM, split-K x2 -> partials -> h = p0+p1+bias
  gemm_bt<4><<<dim3(HID / 128, 25, 2), 256, 0, stream>>>(
      Aim, wPatch, nullptr, part, nullptr, ROWS, HID, CONVK, CONVK / 2);
  reduce2_k<0><<<redGrid, 256, 0, stream>>>(part, patch_b, nullptr, h, MN);

  for (int i = 0; i < NLAYER; ++i) {
    ln_k<1><<<ROWS, 256, 0, stream>>>(h, ln1_g + i * HID, ln1_b + i * HID, xnb, nullptr);
    gemm_bt<2><<<dim3(3072 / 128, 25, 1), 256, 0, stream>>>(
        xnb, wQKV + (size_t)i * 3072 * 1024, qkvbias + i * 3072, nullptr, qkvo,
        ROWS, 3072, HID, HID);
    qkvprep_k<<<dim3(25, 32), 256, 0, stream>>>(qkvo, Qh, Kh, VT);
    flash4_k<<<dim3(32, 25), 256, 0, stream>>>(Qh, Kh, VT, ob);
    // proj, split-K x2 (xnb/qkvo dead now) -> h += proj(ob)+pb
    gemm_bt<4><<<dim3(HID / 128, 25, 2), 256, 0, stream>>>(
        ob, wP + (size_t)i * HID * HID, nullptr, part, nullptr, ROWS, HID, HID, HID / 2);
    reduce2_k<1><<<redGrid, 256, 0, stream>>>(part, pb + i * HID, h, h, MN);
    ln_k<1><<<ROWS, 256, 0, stream>>>(h, ln2_g + i * HID, ln2_b + i * HID, xnb, nullptr);
    gemm_bt<3><<<dim3(MLPD / 128, 25, 1), 256, 0, stream>>>(
        xnb, wF1 + (size_t)i * MLPD * HID, fc1b + i * MLPD, nullptr, mb,
        ROWS, MLPD, HID, HID);
    // fc2, split-K x2 (xnb dead after fc1, qkvo dead) -> h += fc2(mb)+fc2b
    gemm_bt<4><<<dim3(HID / 128, 25, 2), 256, 0, stream>>>(
        mb, wF2 + (size_t)i * HID * MLPD, nullptr, part, nullptr, ROWS, HID, MLPD, MLPD / 2);
    reduce2_k<1><<<redGrid, 256, 0, stream>>>(part, fc2b + i * HID, h, h, MN);
  }
  ln_k<0><<<ROWS, 256, 0, stream>>>(h, lnf_g, lnf_b, nullptr, (float*)d_out);
}